// Round 6
// baseline (2618.843 us; speedup 1.0000x reference)
//
#include <hip/hip_runtime.h>
#include <stdint.h>

#define SLEN    512
#define IDIM    256
#define HDIM    512
#define NROW    256          // 2 sequences x 128 batch rows
#define KP      776          // Ab LDS row stride in halfs (768 + 8)
#define NSTEP   512
#define NGRP    16           // batch groups (16 rows each)
#define GWG     16           // WGs per group
#define TSTR    16           // ints between per-WG tag slots (64 B)

typedef __attribute__((ext_vector_type(8))) _Float16 half8;
typedef __attribute__((ext_vector_type(4))) float   f32x4;
typedef __attribute__((ext_vector_type(4))) int     int4v;

__device__ __forceinline__ float sigm(float x)   { return 1.0f / (1.0f + __expf(-x)); }
__device__ __forceinline__ float tanh_f(float x) { return 2.0f / (1.0f + __expf(-2.0f * x)) - 1.0f; }

__device__ __forceinline__ half8 cvt8(float4 a, float4 b) {
    half8 v;
    v[0] = (_Float16)a.x; v[1] = (_Float16)a.y; v[2] = (_Float16)a.z; v[3] = (_Float16)a.w;
    v[4] = (_Float16)b.x; v[5] = (_Float16)b.y; v[6] = (_Float16)b.z; v[7] = (_Float16)b.w;
    return v;
}

union hu { _Float16 h; unsigned short u; };

// Persistent LSTM. 256 WGs = 16 batch groups (blockIdx&15 -> co-XCD under %8
// round-robin) x 16 column groups. ALL cross-WG stores are sc0 sc1 write-through
// (round-4 proven: updates own-XCD L2 + LLC). Loads: fast path sc0-only (XCD L2)
// gated by a FUNCTIONAL coherence probe (warm-L2 then detect update); slow path
// = round-4 LLC intrinsics. Sync: per-WG monotonic tag stores (no RMW convoy),
// 16-lane parallel poll, bounded + sticky gaveup (no hang possible).
__global__ __launch_bounds__(256, 1)
void lstm_persistent(const float* __restrict__ x0, const float* __restrict__ x1,
                     const float* __restrict__ wih, const float* __restrict__ whh,
                     const float* __restrict__ bih, const float* __restrict__ bhh,
                     _Float16* __restrict__ hb, int* __restrict__ tags,
                     int* __restrict__ probe, int* __restrict__ verd,
                     float* __restrict__ out) {
    __shared__ _Float16 Ab[16 * KP];
    __shared__ int s_fast;

    const int tid  = threadIdx.x;
    const int lane = tid & 63;
    const int w    = tid >> 6;
    const int quad = lane >> 4;
    const int l16  = lane & 15;
    const int igrp = blockIdx.x & 15;    // batch group (co-XCD under %8 round-robin)
    const int jcg  = blockIdx.x >> 4;    // column group 0..15
    const int mtb  = w * 2;

    // ================= functional co-XCD probe (wave 0 only) =================
    if (w == 0) {
        int* myslot = &probe[(igrp * GWG + jcg) * 16];
        // phase 1: publish A via LLC (sc0 sc1 write-through), drained
        if (lane == 0) {
            int a = jcg + 1;
            asm volatile("global_store_dword %0, %1, off sc0 sc1\n\ts_waitcnt vmcnt(0)"
                         :: "v"(myslot), "v"(a) : "memory");
        }
        // phase 2: confirm A via LLC, then warm local L2 with one sc0 read
        if (lane < GWG) {
            const int* sl = &probe[(igrp * GWG + lane) * 16];
            int it = 0;
            while (__hip_atomic_load(sl, __ATOMIC_RELAXED, __HIP_MEMORY_SCOPE_AGENT) != lane + 1
                   && ++it < (1 << 20))
                __builtin_amdgcn_s_sleep(4);
            int dummy;
            asm volatile("global_load_dword %0, %1, off sc0\n\ts_waitcnt vmcnt(0)"
                         : "=&v"(dummy) : "v"(sl) : "memory");
            (void)dummy;
        }
        if (lane == 0)
            __hip_atomic_store(&verd[(igrp * GWG + jcg) * 16], 1,
                               __ATOMIC_RELAXED, __HIP_MEMORY_SCOPE_AGENT);
        // phase 3: wait everyone warmed (via LLC), then publish B
        if (lane < GWG) {
            const int* vs = &verd[(igrp * GWG + lane) * 16];
            int it = 0;
            while (__hip_atomic_load(vs, __ATOMIC_RELAXED, __HIP_MEMORY_SCOPE_AGENT) < 1
                   && ++it < (1 << 20))
                __builtin_amdgcn_s_sleep(4);
        }
        if (lane == 0) {
            int bm = 0x40000000 | (jcg + 1);
            asm volatile("global_store_dword %0, %1, off sc0 sc1\n\ts_waitcnt vmcnt(0)"
                         :: "v"(myslot), "v"(bm) : "memory");
        }
        // phase 4: sc0-only re-read, SHORT bound. Co-XCD: shared L2 was updated by
        // the write-through -> sees B. Cross-XCD: stale warmed line -> timeout.
        int fastl = 1;
        if (lane < GWG) {
            const int* sl = &probe[(igrp * GWG + lane) * 16];
            int v = 0, want = 0x40000000 | (lane + 1);
            for (int it = 0; it < 512; ++it) {
                asm volatile("global_load_dword %0, %1, off sc0\n\ts_waitcnt vmcnt(0)"
                             : "=&v"(v) : "v"(sl) : "memory");
                if (v == want) break;
                __builtin_amdgcn_s_sleep(2);
            }
            fastl = (v == want);
        }
        int allfast = (__ballot((lane < GWG) ? fastl : 1) == ~0ull) ? 1 : 0;
        // phase 5: group consensus via LLC
        if (lane == 0)
            __hip_atomic_store(&verd[(igrp * GWG + jcg) * 16 + 1], 1 + allfast,
                               __ATOMIC_RELAXED, __HIP_MEMORY_SCOPE_AGENT);
        int vv = 2;
        if (lane < GWG) {
            const int* vs = &verd[(igrp * GWG + lane) * 16 + 1];
            int it = 0;
            do {
                vv = __hip_atomic_load(vs, __ATOMIC_RELAXED, __HIP_MEMORY_SCOPE_AGENT);
                if (vv) break;
                __builtin_amdgcn_s_sleep(4);
            } while (++it < (1 << 20));
        }
        int cons = (__ballot((lane < GWG) ? (vv == 2) : 1) == ~0ull) ? 1 : 0;
        if (lane == 0) s_fast = cons;
    }
    __syncthreads();
    const int fast = s_fast;

    // ================= W A-frags: global fp32 -> f16 regs, once =================
    const int q0  = l16 & 3, ccl = l16 >> 2;
    const int gc0 = q0 * HDIM + jcg * 32 + mtb * 4 + ccl;
    const int gc1 = gc0 + 4;
    half8 wf0[24], wf1[24];
#pragma unroll
    for (int kk = 0; kk < 24; ++kk) {
        int k0 = kk * 32 + quad * 8;
        const float* sA = (k0 < IDIM) ? wih + (size_t)gc0 * IDIM + k0
                                      : whh + (size_t)gc0 * HDIM + (k0 - IDIM);
        const float* sB = (k0 < IDIM) ? wih + (size_t)gc1 * IDIM + k0
                                      : whh + (size_t)gc1 * HDIM + (k0 - IDIM);
        wf0[kk] = cvt8(*(const float4*)sA, *(const float4*)(sA + 4));
        wf1[kk] = cvt8(*(const float4*)sB, *(const float4*)(sB + 4));
    }

    float bias0[4], bias1[4];
#pragma unroll
    for (int q = 0; q < 4; ++q) {
        int g0 = q * HDIM + jcg * 32 + mtb * 4 + quad;
        bias0[q] = bih[g0] + bhh[g0];
        bias1[q] = bih[g0 + 4] + bhh[g0 + 4];
    }

    const float* xp  = (igrp < 8) ? x0 : x1;
    const int   brow = (igrp & 7) * 16;
    const int   r0   = tid >> 5;
    const int   o0   = (tid & 31) * 8;
    const int   grow = igrp * 16 + l16;
    const int   cc0  = jcg * 32 + mtb * 4 + quad;
    const int   cc1  = cc0 + 4;
    int* mytag = &tags[(igrp * GWG + jcg) * TSTR];

    float c0 = 0.f, c1 = 0.f;
    int gaveup = 0;   // STICKY spin failsafe: once set, never wait again

#pragma unroll 1
    for (int t = 0; t < NSTEP; ++t) {
        // ---- prefetch x_t (normal cached loads; drains inside the poll) ----
        const float* xr0 = xp + ((size_t)(brow + r0) * SLEN + t) * IDIM + o0;
        const float* xr1 = xr0 + (size_t)8 * SLEN * IDIM;
        float4 pa = *(const float4*)xr0, pb = *(const float4*)(xr0 + 4);
        float4 pc = *(const float4*)xr1, pd = *(const float4*)(xr1 + 4);

        // ---- poll: 16 lanes x 16 per-WG tags >= t (bounded, sticky) ----
        if (t > 0) {
            if (lane < GWG && !gaveup) {
                const int* pt = &tags[(igrp * GWG + lane) * TSTR];
                int it = 0;
                if (fast) {
                    for (;;) {
                        int v;
                        asm volatile("global_load_dword %0, %1, off sc0\n\ts_waitcnt vmcnt(0)"
                                     : "=&v"(v) : "v"(pt) : "memory");
                        if (v >= t) break;
                        __builtin_amdgcn_s_sleep(1);
                        if (++it > (1 << 16)) { gaveup = 1; break; }
                    }
                } else {
                    while (__hip_atomic_load(pt, __ATOMIC_RELAXED, __HIP_MEMORY_SCOPE_AGENT) < t) {
                        __builtin_amdgcn_s_sleep(1);
                        if (++it > (1 << 16)) { gaveup = 1; break; }
                    }
                }
            }
            __builtin_amdgcn_fence(__ATOMIC_ACQUIRE, "workgroup");  // compiler barrier only
        }

        // ---- stage x_t (fp32 -> f16) ----
        *(half8*)&Ab[r0 * KP + o0]       = cvt8(pa, pb);
        *(half8*)&Ab[(r0 + 8) * KP + o0] = cvt8(pc, pd);

        // ---- stage h_{t-1}: fast = sc0 L2 loads, slow = LLC intrinsics (round 4) ----
        {
            const char* hsB = (const char*)(hb + (size_t)((t + 1) & 1) * (NROW * HDIM)
                                               + (size_t)(igrp * 16) * HDIM);
            if (fast) {
                const int4v* hs = (const int4v*)hsB;
                const int4v *a0 = hs + tid,       *a1 = hs + tid + 256,
                            *a2 = hs + tid + 512, *a3 = hs + tid + 768;
                int4v h0, h1, h2, h3;
                asm volatile(
                    "global_load_dwordx4 %0, %4, off sc0\n\t"
                    "global_load_dwordx4 %1, %5, off sc0\n\t"
                    "global_load_dwordx4 %2, %6, off sc0\n\t"
                    "global_load_dwordx4 %3, %7, off sc0\n\t"
                    "s_waitcnt vmcnt(0)"
                    : "=&v"(h0), "=&v"(h1), "=&v"(h2), "=&v"(h3)
                    : "v"(a0), "v"(a1), "v"(a2), "v"(a3) : "memory");
                *(int4v*)&Ab[((tid)       >> 6) * KP + IDIM + ((tid)       & 63) * 8] = h0;
                *(int4v*)&Ab[((tid + 256) >> 6) * KP + IDIM + ((tid + 256) & 63) * 8] = h1;
                *(int4v*)&Ab[((tid + 512) >> 6) * KP + IDIM + ((tid + 512) & 63) * 8] = h2;
                *(int4v*)&Ab[((tid + 768) >> 6) * KP + IDIM + ((tid + 768) & 63) * 8] = h3;
            } else {
                const unsigned long long* hs8 = (const unsigned long long*)hsB;
#pragma unroll
                for (int p = 0; p < 8; ++p) {
                    int c = tid + p * 256;
                    unsigned long long v =
                        __hip_atomic_load(hs8 + c, __ATOMIC_RELAXED, __HIP_MEMORY_SCOPE_AGENT);
                    *(unsigned long long*)&Ab[(c >> 7) * KP + IDIM + (c & 127) * 4] = v;
                }
            }
        }
        __syncthreads();   // barrier A: Ab staged

        // ---- GEMM: each lane's 4 acc regs = gates (i,f,g,o) of one (row,H-col) ----
        f32x4 acc0 = {bias0[0], bias0[1], bias0[2], bias0[3]};
        f32x4 acc1 = {bias1[0], bias1[1], bias1[2], bias1[3]};
        const _Float16* ab = &Ab[l16 * KP + quad * 8];
#pragma unroll
        for (int kk = 0; kk < 24; ++kk) {
            half8 bf = *(const half8*)(ab + kk * 32);
            acc0 = __builtin_amdgcn_mfma_f32_16x16x32_f16(wf0[kk], bf, acc0, 0, 0, 0);
            acc1 = __builtin_amdgcn_mfma_f32_16x16x32_f16(wf1[kk], bf, acc1, 0, 0, 0);
        }

        float i0 = sigm(acc0[0]), f0 = sigm(acc0[1]), g0 = tanh_f(acc0[2]), o0g = sigm(acc0[3]);
        c0 = f0 * c0 + i0 * g0;
        float h0v = o0g * tanh_f(c0);
        float i1 = sigm(acc1[0]), f1 = sigm(acc1[1]), g1 = tanh_f(acc1[2]), o1g = sigm(acc1[3]);
        c1 = f1 * c1 + i1 * g1;
        float h1v = o1g * tanh_f(c1);

        if (t < NSTEP - 1) {
            // h stores: sc0 sc1 write-through (updates own-XCD L2 + LLC), drained
            _Float16* hd = hb + (size_t)(t & 1) * (NROW * HDIM) + (size_t)grow * HDIM;
            hu u0; u0.h = (_Float16)h0v;
            hu u1; u1.h = (_Float16)h1v;
            unsigned v0 = u0.u, v1 = u1.u;
            asm volatile("global_store_short %0, %2, off sc0 sc1\n\t"
                         "global_store_short %1, %3, off sc0 sc1\n\t"
                         "s_waitcnt vmcnt(0)"
                         :: "v"(hd + cc0), "v"(hd + cc1), "v"(v0), "v"(v1) : "memory");
            __syncthreads();   // barrier B: all waves' h stores retired, Ab reads done
            if (tid == 0) {
                // per-WG tag: plain store (no RMW convoy), write-through
                int tv = t + 1;
                asm volatile("global_store_dword %0, %1, off sc0 sc1"
                             :: "v"(mytag), "v"(tv) : "memory");
            }
        } else {
            out[(size_t)grow * HDIM + cc0] = h0v;
            out[(size_t)grow * HDIM + cc1] = h1v;
        }
    }
}

extern "C" void kernel_launch(void* const* d_in, const int* in_sizes, int n_in,
                              void* d_out, int out_size, void* d_ws, size_t ws_size,
                              hipStream_t stream) {
    const float* x0  = (const float*)d_in[0];   // [128,512,256] fp32
    const float* x1  = (const float*)d_in[1];
    const float* wih = (const float*)d_in[2];   // [2048,256]
    const float* whh = (const float*)d_in[3];   // [2048,512]
    const float* bih = (const float*)d_in[4];   // [2048]
    const float* bhh = (const float*)d_in[5];   // [2048]

    // ws: h ping-pong (512 KB f16) + per-WG tags + probe + verdict slots
    _Float16* hb = (_Float16*)d_ws;
    int* tags  = (int*)((char*)d_ws + (size_t)2 * NROW * HDIM * sizeof(_Float16));
    int* probe = tags  + 256 * TSTR;
    int* verd  = probe + 256 * 16;
    size_t zbytes = (size_t)2 * NROW * HDIM * sizeof(_Float16)
                  + (size_t)256 * (TSTR + 16 + 16) * sizeof(int);
    hipMemsetAsync(d_ws, 0, zbytes, stream);   // zero h_{-1} + tags + probe + verd

    lstm_persistent<<<dim3(256), dim3(256), 0, stream>>>(
        x0, x1, wih, whh, bih, bhh, hb, tags, probe, verd, (float*)d_out);
}